// Round 11
// baseline (194.997 us; speedup 1.0000x reference)
//
#include <hip/hip_runtime.h>

typedef unsigned int u32;
typedef unsigned short u16;
typedef __attribute__((ext_vector_type(8))) __bf16 bf16x8;
typedef __attribute__((ext_vector_type(4))) float f32x4;

constexpr int NH = 16;        // heads
constexpr int HDM = 64;       // head dim
constexpr int NSQ = 2048;     // sequence length
constexpr int KD = 1024;      // model dim / GEMM K
constexpr int BHT = 32;       // B*H
constexpr float ROT_C = 13.287712379549449f / 32.0f;  // log2(10000)/32

__device__ __forceinline__ u16 f2bf(float f) {
  u32 u = __float_as_uint(f);
  u += 0x7fffu + ((u >> 16) & 1u);
  return (u16)(u >> 16);
}
__device__ __forceinline__ float bf2f(u16 h) {
  return __uint_as_float(((u32)h) << 16);
}

// fast hw sincos (v_fract + v_sin/v_cos, no libm scratch path).
__device__ __forceinline__ void fast_sincos(float th, float* s, float* c) {
  __sincosf(th, s, c);
}

__device__ __forceinline__ void gl_lds16(const u16* g, u16* l) {
  __builtin_amdgcn_global_load_lds(
      (const __attribute__((address_space(1))) u32*)g,
      (__attribute__((address_space(3))) u32*)l, 16, 0, 0);
}

// swizzled bf16x8 fragment read: row-major tile, row stride rs bytes, 16B chunk cb
__device__ __forceinline__ bf16x8 ldf(const u16* b, int row, int cb, int rs) {
  return *(const bf16x8*)((const char*)b + row * rs + ((cb * 16) ^ ((row & 7) << 4)));
}

// ---------------- elementwise f32 -> bf16 ----------------
__global__ void k_f32_to_bf16(const float* __restrict__ src, u16* __restrict__ dst, int n4) {
  int i = blockIdx.x * 256 + threadIdx.x;
  if (i < n4) {
    float4 v = ((const float4*)src)[i];
    ushort4 o;
    o.x = f2bf(v.x); o.y = f2bf(v.y); o.z = f2bf(v.z); o.w = f2bf(v.w);
    ((ushort4*)dst)[i] = o;
  }
}

// ---------------- merged transpose+convert of the 3 weight tensors ----------------
__global__ void k_transpose3(const float* __restrict__ s0, const float* __restrict__ s1,
                             const float* __restrict__ s2, u16* __restrict__ d0,
                             u16* __restrict__ d1, u16* __restrict__ d2) {
  __shared__ float tile[64][65];
  int bx = blockIdx.x, kt = blockIdx.y * 64;
  const float* src; u16* dst; int srcld, ct;
  if (bx < 48)      { src = s0; dst = d0; srcld = 3072; ct = bx * 64; }
  else if (bx < 80) { src = s1; dst = d1; srcld = 4096; ct = (bx - 48) * 64; }
  else              { src = s2; dst = d2; srcld = 1024; ct = (bx - 80) * 64; }
  int lc = threadIdx.x & 63, rg = threadIdx.x >> 6;
#pragma unroll
  for (int i = 0; i < 16; ++i) {
    int kl = rg * 16 + i;
    tile[kl][lc] = src[(size_t)(kt + kl) * srcld + ct + lc];
  }
  __syncthreads();
#pragma unroll
  for (int i = 0; i < 16; ++i) {
    int cl = rg * 16 + i;
    dst[(size_t)(ct + cl) * 1024 + kt + lc] = f2bf(tile[lc][cl]);
  }
}

// ================= projection GEMM: 128x256 tile, BK=64, coarse counted-vmcnt =================
__device__ __forceinline__ void stage_v3(const u16* __restrict__ gA, const u16* __restrict__ gB,
                                         u16* AL, u16* BL, int mb, int nb, int kt, int tid) {
#pragma unroll
  for (int l = 0; l < 2; ++l) {
    int i = tid + l * 512;          // chunk index 0..1023
    int row = i >> 3, cb = i & 7;
    int col = (cb ^ (row & 7)) << 3;
    gl_lds16(gA + (size_t)(mb + row) * KD + kt * 64 + col, AL + i * 8);
  }
#pragma unroll
  for (int l = 0; l < 4; ++l) {
    int i = tid + l * 512;          // chunk index 0..2047
    int row = i >> 3, cb = i & 7;
    int col = (cb ^ (row & 7)) << 3;
    gl_lds16(gB + (size_t)(nb + row) * KD + kt * 64 + col, BL + i * 8);
  }
}

__device__ __forceinline__ void compute_v3(const u16* AL, const u16* BL,
                                           f32x4 (&acc)[4][4], int wr, int wc, int g, int q) {
#pragma unroll
  for (int ks = 0; ks < 2; ++ks) {
    bf16x8 af[4], bfr[4];
#pragma unroll
    for (int nf = 0; nf < 4; ++nf)
      bfr[nf] = ldf(BL, wc * 64 + nf * 16 + q, ks * 4 + g, 128);
#pragma unroll
    for (int mf = 0; mf < 4; ++mf)
      af[mf] = ldf(AL, wr * 64 + mf * 16 + q, ks * 4 + g, 128);
    __builtin_amdgcn_s_setprio(1);
#pragma unroll
    for (int mf = 0; mf < 4; ++mf)
#pragma unroll
      for (int nf = 0; nf < 4; ++nf)
        acc[mf][nf] = __builtin_amdgcn_mfma_f32_16x16x32_bf16(af[mf], bfr[nf], acc[mf][nf], 0, 0, 0);
    __builtin_amdgcn_s_setprio(0);
  }
}

__global__ __launch_bounds__(512) void k_gemm0_v3(const u16* __restrict__ A,
                                                  const u16* __restrict__ Bt,
                                                  u16* __restrict__ o0, u16* __restrict__ o1,
                                                  u16* __restrict__ o2, u16* __restrict__ o3,
                                                  u16* __restrict__ o4) {
  __shared__ __align__(16) u16 AL[2][8192];    // 128 x 64
  __shared__ __align__(16) u16 BL[2][16384];   // 256 x 64
  int bid = blockIdx.x;
  int swz = (bid & 7) * 80 + (bid >> 3);       // XCD-bijective (640 % 8 == 0)
  int nt = swz % 20, mt = swz / 20;            // nt in [0,20), mt in [0,32)
  int tid = threadIdx.x, w = tid >> 6, lane = tid & 63;
  int g = lane >> 4, q = lane & 15;
  int wr = w >> 2, wc = w & 3;                 // 2 M-waves x 4 N-waves
  int mb = mt * 128, nb = nt * 256;

  f32x4 acc[4][4];
#pragma unroll
  for (int m = 0; m < 4; ++m)
#pragma unroll
    for (int n = 0; n < 4; ++n) acc[m][n] = (f32x4){0.f, 0.f, 0.f, 0.f};

  stage_v3(A, Bt, AL[0], BL[0], mb, nb, 0, tid);
  stage_v3(A, Bt, AL[1], BL[1], mb, nb, 1, tid);
  asm volatile("s_waitcnt vmcnt(6)" ::: "memory");
  asm volatile("s_barrier" ::: "memory");
  __builtin_amdgcn_sched_barrier(0);

#define GBODY(KT, PBUF)                                                     \
  {                                                                         \
    compute_v3(AL[PBUF], BL[PBUF], acc, wr, wc, g, q);                      \
    asm volatile("s_barrier" ::: "memory");                                 \
    if ((KT) + 2 < 16) {                                                    \
      stage_v3(A, Bt, AL[PBUF], BL[PBUF], mb, nb, (KT) + 2, tid);           \
      asm volatile("s_waitcnt vmcnt(6)" ::: "memory");                      \
    } else if ((KT) == 14) {                                                \
      asm volatile("s_waitcnt vmcnt(0)" ::: "memory");                      \
    }                                                                       \
    asm volatile("s_barrier" ::: "memory");                                 \
    __builtin_amdgcn_sched_barrier(0);                                      \
  }

  for (int it = 0; it < 8; ++it) {
    GBODY(2 * it, 0);
    GBODY(2 * it + 1, 1);
  }
#undef GBODY

  // epilogue: 5-way split per column-tensor
#pragma unroll
  for (int nf = 0; nf < 4; ++nf) {
    int c = nt * 256 + wc * 64 + nf * 16 + q;
    int t = c >> 10;
    if (t == 1) {
      // K: fused rotary, write Kr [b][h][n][d]
      int rem = c & 1023;
      int hh = rem >> 6, dd = rem & 63;
      float invf = exp2f(-(float)(dd >> 1) * ROT_C);
      float sgn = (dd & 1) ? 1.0f : -1.0f;
      size_t hoff = (size_t)hh * NSQ * HDM + dd;
#pragma unroll
      for (int mf = 0; mf < 4; ++mf)
#pragma unroll
        for (int r = 0; r < 4; ++r) {
          int row = mt * 128 + wr * 64 + mf * 16 + g * 4 + r;
          int b = row >> 11, nn = row & 2047;
          float mine = acc[mf][nf][r];
          float part = __shfl_xor(mine, 1);
          float s, cc;
          fast_sincos((float)nn * invf, &s, &cc);
          o1[(size_t)b * NH * NSQ * HDM + hoff + (size_t)nn * HDM] = f2bf(mine * cc + sgn * part * s);
        }
    } else if (t == 2) {
      // V -> transposed [bh][d][n]
      int rem = c & 1023;
      int hh = rem >> 6, dd = rem & 63;
#pragma unroll
      for (int mf = 0; mf < 4; ++mf)
#pragma unroll
        for (int r = 0; r < 4; ++r) {
          int row = mt * 128 + wr * 64 + mf * 16 + g * 4 + r;
          int b = row >> 11, nn = row & 2047;
          o2[((size_t)(b * NH + hh) * HDM + dd) * NSQ + nn] = f2bf(acc[mf][nf][r]);
        }
    } else {
      u16* dst = (t == 0) ? o0 : ((t == 3) ? o3 : o4);
      int rem = c & 1023;
      size_t hoff = (size_t)(rem >> 6) * NSQ * HDM + (rem & 63);
#pragma unroll
      for (int mf = 0; mf < 4; ++mf)
#pragma unroll
        for (int r = 0; r < 4; ++r) {
          int row = mt * 128 + wr * 64 + mf * 16 + g * 4 + r;
          int b = row >> 11, nn = row & 2047;
          dst[(size_t)b * NH * NSQ * HDM + hoff + (size_t)nn * HDM] = f2bf(acc[mf][nf][r]);
        }
    }
  }
}

// ================= output GEMM: 64x128 tile, m97 schedule, 512 blocks =================
__device__ __forceinline__ void gemm_stage_o(const u16* __restrict__ A, const u16* __restrict__ Bt,
                                             u16* Albuf, u16* Blbuf, int mt, int nt, int kt,
                                             int tid) {
  {
    int i = tid;                       // A: 64x32 = 256 chunks
    int row = i >> 2;
    int ke = (i & 3) * 8;
    int grow = mt * 64 + row;
    int k = kt * 32 + ke;
    const u16* ga = A + ((size_t)((grow >> 11) * NH + (k >> 6)) * NSQ + (grow & 2047)) * HDM + (k & 63);
    gl_lds16(ga, Albuf + i * 8);
  }
#pragma unroll
  for (int l = 0; l < 2; ++l) {        // B: 128x32 = 512 chunks
    int i = tid + l * 256;
    int row = i >> 2;
    int ke = (i & 3) * 8;
    const u16* gb = Bt + (size_t)(nt * 128 + row) * KD + kt * 32 + ke;
    gl_lds16(gb, Blbuf + i * 8);
  }
}

__device__ __forceinline__ void gemm_compute_o(const u16* Albuf, const u16* Blbuf,
                                               f32x4 acc[2][4], int wr, int wc, int g, int q) {
  bf16x8 af[2], bfr[4];
#pragma unroll
  for (int m = 0; m < 2; ++m)
    af[m] = *(const bf16x8*)(Albuf + (wr * 32 + m * 16 + q) * 32 + g * 8);
#pragma unroll
  for (int n = 0; n < 4; ++n)
    bfr[n] = *(const bf16x8*)(Blbuf + (wc * 64 + n * 16 + q) * 32 + g * 8);
#pragma unroll
  for (int m = 0; m < 2; ++m)
#pragma unroll
    for (int n = 0; n < 4; ++n)
      acc[m][n] = __builtin_amdgcn_mfma_f32_16x16x32_bf16(af[m], bfr[n], acc[m][n], 0, 0, 0);
}

__global__ __launch_bounds__(256) void k_gemm_out(const u16* __restrict__ A, const u16* __restrict__ Bt,
                                                  const float* __restrict__ bias,
                                                  float* __restrict__ Cout) {
  __shared__ __align__(16) u16 Al[2][2048];    // 64 x 32
  __shared__ __align__(16) u16 Bl[2][4096];    // 128 x 32
  int nt = blockIdx.x, mt = blockIdx.y;
  int tid = threadIdx.x, w = tid >> 6, lane = tid & 63;
  int g = lane >> 4, q = lane & 15, wr = w >> 1, wc = w & 1;
  f32x4 acc[2][4];
#pragma unroll
  for (int m = 0; m < 2; ++m)
#pragma unroll
    for (int n = 0; n < 4; ++n) acc[m][n] = (f32x4){0.f, 0.f, 0.f, 0.f};

  gemm_stage_o(A, Bt, Al[0], Bl[0], mt, nt, 0, tid);
  __syncthreads();
  int cur = 0;
  for (int kt = 1; kt < 32; ++kt) {
    gemm_stage_o(A, Bt, Al[cur ^ 1], Bl[cur ^ 1], mt, nt, kt, tid);
    gemm_compute_o(Al[cur], Bl[cur], acc, wr, wc, g, q);
    __syncthreads();
    cur ^= 1;
  }
  gemm_compute_o(Al[cur], Bl[cur], acc, wr, wc, g, q);

#pragma unroll
  for (int nf = 0; nf < 4; ++nf) {
    int c = nt * 128 + wc * 64 + nf * 16 + q;
    float bv = bias[c];
#pragma unroll
    for (int mf = 0; mf < 2; ++mf)
#pragma unroll
      for (int r = 0; r < 4; ++r) {
        int row = mt * 64 + wr * 32 + mf * 16 + g * 4 + r;
        Cout[(size_t)row * 1024 + c] = acc[mf][nf][r] + bv;
      }
  }
}

// ---------------- chunk pass 1: per-chunk sum of outer products kk ⊗ vk ----------------
__global__ __launch_bounds__(256) void k_chunk_outer(const u16* __restrict__ Kk,
                                                     const u16* __restrict__ Vk,
                                                     float* __restrict__ Mc) {
  int bhc = blockIdx.x;  // 512 = bh*16 + c
  __shared__ float kk[128][64];
  __shared__ float vv[128][64];
  int tid = threadIdx.x;
  size_t base = ((size_t)(bhc >> 4) * NSQ + (size_t)(bhc & 15) * 128) * HDM;
  for (int i = tid; i < 2048; i += 256) {
    int r = i >> 4, c4 = (i & 15) * 4;
    ushort4 a = ((const ushort4*)(Kk + base))[i];
    kk[r][c4] = bf2f(a.x); kk[r][c4 + 1] = bf2f(a.y); kk[r][c4 + 2] = bf2f(a.z); kk[r][c4 + 3] = bf2f(a.w);
    ushort4 b = ((const ushort4*)(Vk + base))[i];
    vv[r][c4] = bf2f(b.x); vv[r][c4 + 1] = bf2f(b.y); vv[r][c4 + 2] = bf2f(b.z); vv[r][c4 + 3] = bf2f(b.w);
  }
  __syncthreads();
  int i0 = (tid >> 4) * 4, j0 = (tid & 15) * 4;
  float a2[4][4];
#pragma unroll
  for (int di = 0; di < 4; ++di)
#pragma unroll
    for (int dj = 0; dj < 4; ++dj) a2[di][dj] = 0.f;
  for (int m = 0; m < 128; ++m) {
    float ka[4], vb[4];
#pragma unroll
    for (int d = 0; d < 4; ++d) { ka[d] = kk[m][i0 + d]; vb[d] = vv[m][j0 + d]; }
#pragma unroll
    for (int di = 0; di < 4; ++di)
#pragma unroll
      for (int dj = 0; dj < 4; ++dj) a2[di][dj] += ka[di] * vb[dj];
  }
  float* out = Mc + (size_t)bhc * 4096;
#pragma unroll
  for (int di = 0; di < 4; ++di) {
    float4 v = make_float4(a2[di][0], a2[di][1], a2[di][2], a2[di][3]);
    *(float4*)(out + (i0 + di) * 64 + j0) = v;
  }
}

// ---------------- fused chunk pass: local prefix + norm + y + rotary ----------------
// Replaces prefix2 + norm + yv2: each (bh,c) block computes S_state = 8I + sum_{cc<c} Mc,
// invn via MFMA gram/bilinear + scan, then Y = (Q S^T + mask(Q Vk^T) Kk) * invn, rotary*0.125.
__global__ __launch_bounds__(256) void k_chunk_fused(const u16* __restrict__ Qb,
                                                     const u16* __restrict__ Kk,
                                                     const u16* __restrict__ Vk,
                                                     const float* __restrict__ Mc,
                                                     u16* __restrict__ Qro) {
  __shared__ __align__(16) u16 KkL[128 * 64];
  __shared__ __align__(16) u16 VkL[128 * 64];  // Vk; later reused for KkT (64 x 256B)
  __shared__ __align__(16) u16 QL[128 * 64];
  __shared__ __align__(16) u16 SL[64 * 64];
  __shared__ __align__(16) u16 PL[128 * 128];
  __shared__ float prebuf[128][2];
  __shared__ float bilbuf[128][2];
  __shared__ float sc[128];
  __shared__ float red[4];
  __shared__ float inv[128];
  int bhc = blockIdx.x;
  int bh = bhc >> 4, c = bhc & 15;
  int tid = threadIdx.x, w = tid >> 6, lane = tid & 63;
  int g = lane >> 4, q = lane & 15;
  size_t base = (size_t)bhc * 8192;

  // stage Kk, Vk, Q (swizzled rs=128)
  for (int ic = tid; ic < 1024; ic += 256) {
    int row = ic >> 3, cb = ic & 7;
    int off = row * 128 + ((cb * 16) ^ ((row & 7) << 4));
    *(uint4*)((char*)KkL + off) = ((const uint4*)(Kk + base))[ic];
    *(uint4*)((char*)VkL + off) = ((const uint4*)(Vk + base))[ic];
    *(uint4*)((char*)QL + off) = ((const uint4*)(Qb + base))[ic];
  }
  // local prefix: S_state = 8*I + sum_{cc<c} Mc[bh][cc] -> SL (bf16) + ss
  float s4[4][4];
#pragma unroll
  for (int l = 0; l < 4; ++l) {
    int i = tid + l * 256;
    int row = i >> 4, c4 = (i & 15) * 4;
#pragma unroll
    for (int j = 0; j < 4; ++j) s4[l][j] = (row == c4 + j) ? 8.0f : 0.0f;
  }
  for (int cc = 0; cc < c; ++cc) {
    const float4* Mg = (const float4*)(Mc + ((size_t)bh * 16 + cc) * 4096);
#pragma unroll
    for (int l = 0; l < 4; ++l) {
      float4 v = Mg[tid + l * 256];
      s4[l][0] += v.x; s4[l][1] += v.y; s4[l][2] += v.z; s4[l][3] += v.w;
    }
  }
  float ss = 0.f;
#pragma unroll
  for (int l = 0; l < 4; ++l) {
    int i = tid + l * 256;
    int row = i >> 4, c8 = (i & 15) * 8;
    ss += s4[l][0] * s4[l][0] + s4[l][1] * s4[l][1] + s4[l][2] * s4[l][2] + s4[l][3] * s4[l][3];
    u32 lo = (u32)f2bf(s4[l][0]) | ((u32)f2bf(s4[l][1]) << 16);
    u32 hi = (u32)f2bf(s4[l][2]) | ((u32)f2bf(s4[l][3]) << 16);
    *(uint2*)((char*)SL + row * 128 + (c8 ^ ((row & 7) << 4))) = make_uint2(lo, hi);
  }
#pragma unroll
  for (int d = 1; d < 64; d <<= 1) ss += __shfl_xor(ss, d);
  if (lane == 0) red[w] = ss;
  __syncthreads();

  int wr = w >> 1, wc = w & 1;
  bf16x8 ka[4][2], va[4][2];
#pragma unroll
  for (int mf = 0; mf < 4; ++mf)
#pragma unroll
    for (int ks = 0; ks < 2; ++ks) {
      ka[mf][ks] = ldf(KkL, wr * 64 + mf * 16 + q, ks * 4 + g, 128);
      va[mf][ks] = ldf(VkL, wr * 64 + mf * 16 + q, ks * 4 + g, 128);
    }

  // G = (Kk Kk^T) o (Vk Vk^T), masked row-prefix accumulation
  float pracc[4][4];
#pragma unroll
  for (int mf = 0; mf < 4; ++mf)
#pragma unroll
    for (int r = 0; r < 4; ++r) pracc[mf][r] = 0.f;
  for (int pf = 0; pf < 4; ++pf) {
    bf16x8 kb0 = ldf(KkL, wc * 64 + pf * 16 + q, g, 128);
    bf16x8 kb1 = ldf(KkL, wc * 64 + pf * 16 + q, 4 + g, 128);
    bf16x8 vb0 = ldf(VkL, wc * 64 + pf * 16 + q, g, 128);
    bf16x8 vb1 = ldf(VkL, wc * 64 + pf * 16 + q, 4 + g, 128);
#pragma unroll
    for (int mf = 0; mf < 4; ++mf) {
      f32x4 a1 = (f32x4){0.f, 0.f, 0.f, 0.f}, b1 = (f32x4){0.f, 0.f, 0.f, 0.f};
      a1 = __builtin_amdgcn_mfma_f32_16x16x32_bf16(ka[mf][0], kb0, a1, 0, 0, 0);
      a1 = __builtin_amdgcn_mfma_f32_16x16x32_bf16(ka[mf][1], kb1, a1, 0, 0, 0);
      b1 = __builtin_amdgcn_mfma_f32_16x16x32_bf16(va[mf][0], vb0, b1, 0, 0, 0);
      b1 = __builtin_amdgcn_mfma_f32_16x16x32_bf16(va[mf][1], vb1, b1, 0, 0, 0);
#pragma unroll
      for (int r = 0; r < 4; ++r) {
        int m = wr * 64 + mf * 16 + g * 4 + r;
        int p = wc * 64 + pf * 16 + q;
        float gv = a1[r] * b1[r];
        float coef = (p < m) ? 1.f : ((p == m) ? 0.5f : 0.f);
        pracc[mf][r] += coef * gv;
      }
    }
  }
#pragma unroll
  for (int mf = 0; mf < 4; ++mf)
#pragma unroll
    for (int r = 0; r < 4; ++r) {
      float v = pracc[mf][r];
      v += __shfl_xor(v, 1); v += __shfl_xor(v, 2); v += __shfl_xor(v, 4); v += __shfl_xor(v, 8);
      pracc[mf][r] = v;
    }
  if (q == 0) {
#pragma unroll
    for (int mf = 0; mf < 4; ++mf)
#pragma unroll
      for (int r = 0; r < 4; ++r) prebuf[wr * 64 + mf * 16 + g * 4 + r][wc] = pracc[mf][r];
  }

  // U = Vk S^T ; bil_m = sum_j Kk[m][j]*U[m][j]
  float bacc[4][4];
#pragma unroll
  for (int mf = 0; mf < 4; ++mf)
#pragma unroll
    for (int r = 0; r < 4; ++r) bacc[mf][r] = 0.f;
  for (int jf = 0; jf < 2; ++jf) {
    bf16x8 sb0 = ldf(SL, wc * 32 + jf * 16 + q, g, 128);
    bf16x8 sb1 = ldf(SL, wc * 32 + jf * 16 + q, 4 + g, 128);
#pragma unroll
    for (int mf = 0; mf < 4; ++mf) {
      f32x4 u = (f32x4){0.f, 0.f, 0.f, 0.f};
      u = __builtin_amdgcn_mfma_f32_16x16x32_bf16(va[mf][0], sb0, u, 0, 0, 0);
      u = __builtin_amdgcn_mfma_f32_16x16x32_bf16(va[mf][1], sb1, u, 0, 0, 0);
#pragma unroll
      for (int r = 0; r < 4; ++r) {
        int m = wr * 64 + mf * 16 + g * 4 + r;
        int j = wc * 32 + jf * 16 + q;
        float kkv = bf2f(*(const u16*)((const char*)KkL + m * 128 + ((j * 2) ^ ((m & 7) << 4))));
        bacc[mf][r] += u[r] * kkv;
      }
    }
  }
#pragma unroll
  for (int mf = 0; mf < 4; ++mf)
#pragma unroll
    for (int r = 0; r < 4; ++r) {
      float v = bacc[mf][r];
      v += __shfl_xor(v, 1); v += __shfl_xor(v, 2); v += __shfl_xor(v, 4); v += __shfl_xor(v, 8);
      bacc[mf][r] = v;
    }
  if (q == 0) {
#pragma unroll
    for (int mf = 0; mf < 4; ++mf)
#pragma unroll
      for (int r = 0; r < 4; ++r) bilbuf[wr * 64 + mf * 16 + g * 4 + r][wc] = bacc[mf][r];
  }
  __syncthreads();

  // inclusive scan of e_m -> inv[n] in LDS
  if (tid < 128)
    sc[tid] = 2.f * (prebuf[tid][0] + prebuf[tid][1] + bilbuf[tid][0] + bilbuf[tid][1]);
  __syncthreads();
  for (int off = 1; off < 128; off <<= 1) {
    float add = 0.f;
    if (tid < 128 && tid >= off) add = sc[tid - off];
    __syncthreads();
    if (tid < 128) sc[tid] += add;
    __syncthreads();
  }
  if (tid < 128) {
    float n0 = red[0] + red[1] + red[2] + red[3];
    inv[tid] = 1.f / (sqrtf(n0 + sc[tid]) + 1e-8f);
  }

  // Pt = Vk * Q^T (va reused) -> mask -> PL ; KkT restage into VkL region
  f32x4 pacc[4][4];
#pragma unroll
  for (int mf = 0; mf < 4; ++mf)
#pragma unroll
    for (int nf = 0; nf < 4; ++nf) pacc[mf][nf] = (f32x4){0.f, 0.f, 0.f, 0.f};
#pragma unroll
  for (int ks = 0; ks < 2; ++ks) {
    bf16x8 bq[4];
#pragma unroll
    for (int nf = 0; nf < 4; ++nf) bq[nf] = ldf(QL, wc * 64 + nf * 16 + q, ks * 4 + g, 128);
#pragma unroll
    for (int mf = 0; mf < 4; ++mf)
#pragma unroll
      for (int nf = 0; nf < 4; ++nf)
        pacc[mf][nf] = __builtin_amdgcn_mfma_f32_16x16x32_bf16(va[mf][ks], bq[nf], pacc[mf][nf], 0, 0, 0);
  }
#pragma unroll
  for (int mf = 0; mf < 4; ++mf)
#pragma unroll
    for (int nf = 0; nf < 4; ++nf) {
      int m0 = wr * 64 + mf * 16 + g * 4;
      int n = wc * 64 + nf * 16 + q;
      float v0 = (m0 + 0 <= n) ? pacc[mf][nf][0] : 0.f;
      float v1 = (m0 + 1 <= n) ? pacc[mf][nf][1] : 0.f;
      float v2 = (m0 + 2 <= n) ? pacc[mf][nf][2] : 0.f;
      float v3 = (m0 + 3 <= n) ? pacc[mf][nf][3] : 0.f;
      u32 lo = (u32)f2bf(v0) | ((u32)f2bf(v1) << 16);
      u32 hi = (u32)f2bf(v2) | ((u32)f2bf(v3) << 16);
      *(uint2*)((char*)PL + n * 256 + ((m0 * 2) ^ ((n & 7) << 4))) = make_uint2(lo, hi);
    }
  for (int i = tid; i < 2048; i += 256) {
    int r = i >> 4, c4 = (i & 15) * 4;
    ushort4 kv = ((const ushort4*)(Kk + base))[i];
    *(u16*)((char*)VkL + (c4 + 0) * 256 + ((r * 2) ^ (((c4 + 0) & 7) << 4))) = kv.x;
    *(u16*)((char*)VkL + (c4 + 1) * 256 + ((r * 2) ^ (((c4 + 1) & 7) << 4))) = kv.y;
    *(u16*)((char*)VkL + (c4 + 2) * 256 + ((r * 2) ^ (((c4 + 2) & 7) << 4))) = kv.z;
    *(u16*)((char*)VkL + (c4 + 3) * 256 + ((r * 2) ^ (((c4 + 3) & 7) << 4))) = kv.w;
  }
  __syncthreads();

  // Y[n][j] = sum_i Q[n][i] S[j][i] + sum_m P[n][m] KkT[j][m]
  f32x4 yacc[4][2];
#pragma unroll
  for (int nf = 0; nf < 4; ++nf)
#pragma unroll
    for (int jf = 0; jf < 2; ++jf) yacc[nf][jf] = (f32x4){0.f, 0.f, 0.f, 0.f};
#pragma unroll
  for (int ks = 0; ks < 2; ++ks) {
    bf16x8 aq[4], bs[2];
#pragma unroll
    for (int nf = 0; nf < 4; ++nf) aq[nf] = ldf(QL, wr * 64 + nf * 16 + q, ks * 4 + g, 128);
#pragma unroll
    for (int jf = 0; jf < 2; ++jf) bs[jf] = ldf(SL, wc * 32 + jf * 16 + q, ks * 4 + g, 128);
#pragma unroll
    for (int nf = 0; nf < 4; ++nf)
#pragma unroll
      for (int jf = 0; jf < 2; ++jf)
        yacc[nf][jf] = __builtin_amdgcn_mfma_f32_16x16x32_bf16(aq[nf], bs[jf], yacc[nf][jf], 0, 0, 0);
  }
#pragma unroll
  for (int ks = 0; ks < 4; ++ks) {
    bf16x8 ap[4], bk[2];
#pragma unroll
    for (int nf = 0; nf < 4; ++nf) ap[nf] = ldf(PL, wr * 64 + nf * 16 + q, ks * 4 + g, 256);
#pragma unroll
    for (int jf = 0; jf < 2; ++jf) bk[jf] = ldf(VkL, wc * 32 + jf * 16 + q, ks * 4 + g, 256);
#pragma unroll
    for (int nf = 0; nf < 4; ++nf)
#pragma unroll
      for (int jf = 0; jf < 2; ++jf)
        yacc[nf][jf] = __builtin_amdgcn_mfma_f32_16x16x32_bf16(ap[nf], bk[jf], yacc[nf][jf], 0, 0, 0);
  }
  // epilogue: *inv[n], rotary (pair via shfl_xor 1), *0.125, write Qro
#pragma unroll
  for (int nf = 0; nf < 4; ++nf)
#pragma unroll
    for (int jf = 0; jf < 2; ++jf) {
      int j = wc * 32 + jf * 16 + q;
      float invf = exp2f(-(float)(j >> 1) * ROT_C);
      float sgn = (j & 1) ? 1.0f : -1.0f;
#pragma unroll
      for (int r = 0; r < 4; ++r) {
        int n = wr * 64 + nf * 16 + g * 4 + r;
        float val = yacc[nf][jf][r] * inv[n];
        float part = __shfl_xor(val, 1);
        int ng = c * 128 + n;
        float s, cc2;
        fast_sincos((float)ng * invf, &s, &cc2);
        Qro[base + (size_t)n * 64 + j] = f2bf((val * cc2 + sgn * part * s) * 0.125f);
      }
    }
}

// ---------------- causal flash attention v3: phase split across blockIdx.z ----------------
__global__ __launch_bounds__(512) void k_attn3(const u16* __restrict__ Qr, const u16* __restrict__ Kr,
                                               const u16* __restrict__ Vt, u16* __restrict__ Ob) {
  __shared__ __align__(16) u16 QL[128 * 64];
  __shared__ __align__(16) u16 KL[2][64 * 64];
  __shared__ __align__(16) u16 VL[2][64 * 64];
  __shared__ __align__(16) u16 PLa[8][16 * 64];
  int bh = blockIdx.x, pair = blockIdx.y, phase = blockIdx.z;
  int tid = threadIdx.x, w = tid >> 6, lane = tid & 63;
  int g = lane >> 4, q16 = lane & 15;
  const u16* Qg_base = Qr + (size_t)bh * NSQ * HDM;
  const u16* Kg_base = Kr + (size_t)bh * NSQ * HDM;
  const u16* VTg_base = Vt + (size_t)bh * HDM * NSQ;  // [d][n]
  u16* Og_base = Ob + (size_t)bh * NSQ * HDM;
  u16* Pw = PLa[w];
  int srow = tid >> 3, scb = tid & 7;  // staging row/chunk for 64x64 tiles

  int t = phase ? (15 - pair) : pair;
  int qbase = t * 128;
  int nkt = 2 * t + 2;
  int lastkt_w = (qbase + w * 16 + 15) >> 6;
  int qg_ = qbase + w * 16 + q16;

  {
    const u16* Qg = Qg_base + qbase * 64;
#pragma unroll
    for (int it = 0; it < 2; ++it) {
      int c = it * 512 + tid;
      int row = c >> 3, cb = c & 7;
      gl_lds16(Qg + row * 64 + ((cb ^ (row & 7)) << 3), QL + c * 8);
    }
  }
  gl_lds16(Kg_base + srow * 64 + ((scb ^ (srow & 7)) << 3), KL[0] + tid * 8);
  gl_lds16(VTg_base + (size_t)srow * NSQ + ((scb ^ (srow & 7)) << 3), VL[0] + tid * 8);
  __syncthreads();

  bf16x8 qf[2];
  qf[0] = ldf(QL, w * 16 + q16, g, 128);
  qf[1] = ldf(QL, w * 16 + q16, 4 + g, 128);

  f32x4 o[4];
#pragma unroll
  for (int df = 0; df < 4; ++df) o[df] = (f32x4){0.f, 0.f, 0.f, 0.f};
  float m_run = -3.0e38f, l_run = 0.f;

  int cur = 0;
  for (int kt = 0; kt < nkt; ++kt) {
    if (kt + 1 < nkt) {
      gl_lds16(Kg_base + (kt + 1) * 4096 + srow * 64 + ((scb ^ (srow & 7)) << 3),
               KL[cur ^ 1] + tid * 8);
      gl_lds16(VTg_base + (size_t)srow * NSQ + (kt + 1) * 64 + ((scb ^ (srow & 7)) << 3),
               VL[cur ^ 1] + tid * 8);
    }
    if (kt <= lastkt_w) {
      const u16* Kbuf = KL[cur];
      const u16* Vbuf = VL[cur];
      f32x4 st[4];
#pragma unroll
      for (int kf = 0; kf < 4; ++kf) {
        f32x4 s = (f32x4){0.f, 0.f, 0.f, 0.f};
        s = __builtin_amdgcn_mfma_f32_16x16x32_bf16(ldf(Kbuf, kf * 16 + q16, g, 128), qf[0], s, 0, 0, 0);
        s = __builtin_amdgcn_mfma_f32_16x16x32_bf16(ldf(Kbuf, kf * 16 + q16, 4 + g, 128), qf[1], s, 0, 0, 0);
        st[kf] = s;
      }
      float smax = -1e30f;
      bool needmask = (kt * 64 + 63 > qbase + w * 16);
      if (needmask) {
#pragma unroll
        for (int kf = 0; kf < 4; ++kf)
#pragma unroll
          for (int r = 0; r < 4; ++r) {
            int keyg = kt * 64 + kf * 16 + g * 4 + r;
            float sv = st[kf][r];
            sv = (keyg <= qg_) ? sv : -1e30f;
            st[kf][r] = sv;
            smax = fmaxf(smax, sv);
          }
      } else {
#pragma unroll
        for (int kf = 0; kf < 4; ++kf)
#pragma unroll
          for (int r = 0; r < 4; ++r) smax = fmaxf(smax, st[kf][r]);
      }
      smax = fmaxf(smax, __shfl_xor(smax, 16));
      smax = fmaxf(smax, __shfl_xor(smax, 32));
      float mnew = fmaxf(m_run, smax);
      float corr = __expf(m_run - mnew);
      float ls = 0.f;
#pragma unroll
      for (int kf = 0; kf < 4; ++kf)
#pragma unroll
        for (int r = 0; r < 4; ++r) {
          float p = __expf(st[kf][r] - mnew);
          st[kf][r] = p;
          ls += p;
        }
      ls += __shfl_xor(ls, 16);
      ls += __shfl_xor(ls, 32);
      m_run = mnew;
      l_run = l_run * corr + ls;
#pragma unroll
      for (int df = 0; df < 4; ++df) {
        o[df][0] *= corr; o[df][1] *= corr; o[df][2] *= corr; o[df][3] *= corr;
      }
#pragma unroll
      for (int kf = 0; kf < 4; ++kf) {
        u32 lo = (u32)f2bf(st[kf][0]) | ((u32)f2bf(st[kf][1]) << 16);
        u32 hi = (u32)f2bf(st[kf][2]) | ((u32)f2bf(st[kf][3]) << 16);
        int ba = q16 * 128 + ((kf * 32 + g * 8) ^ ((q16 & 7) << 4));
        *(u32*)((char*)Pw + ba) = lo;
        *(u32*)((char*)Pw + ba + 4) = hi;
      }
#pragma unroll
      for (int kc = 0; kc < 2; ++kc) {
        bf16x8 pf = ldf(Pw, q16, kc * 4 + g, 128);
#pragma unroll
        for (int df = 0; df < 4; ++df) {
          bf16x8 vf = ldf(Vbuf, df * 16 + q16, kc * 4 + g, 128);
          o[df] = __builtin_amdgcn_mfma_f32_16x16x32_bf16(vf, pf, o[df], 0, 0, 0);
        }
      }
    }
    __syncthreads();
    cur ^= 1;
  }
  float invl = 1.0f / l_run;
  u16* Og = Og_base + (size_t)(qbase + w * 16 + q16) * HDM;
#pragma unroll
  for (int df = 0; df < 4; ++df)
#pragma unroll
    for (int r = 0; r < 4; ++r) Og[df * 16 + g * 4 + r] = f2bf(o[df][r] * invl);
}

// ---------------- launcher ----------------
extern "C" void kernel_launch(void* const* d_in, const int* in_sizes, int n_in,
                              void* d_out, int out_size, void* d_ws, size_t ws_size,
                              hipStream_t stream) {
  const float* X = (const float*)d_in[0];
  const float* w_qkv = (const float*)d_in[1];
  const float* w_kvkv = (const float*)d_in[2];
  const float* w_out = (const float*)d_in[3];
  const float* b_out = (const float*)d_in[4];
  float* out = (float*)d_out;
  char* ws = (char*)d_ws;

  u16* Xb  = (u16*)(ws + 0);                        // 8 MB   (later aliased by Ob)
  u16* WbT = (u16*)(ws + 8388608);                  // 10 MB  (later aliased by Mc)
  u16* WoT = (u16*)(ws + 18874368);                 // 2 MB
  u16* Qb  = (u16*)(ws + 20971520);                 // 8 MB
  u16* Vtb = (u16*)(ws + 37748736);                 // 8 MB (V transposed [bh][d][n])
  u16* Kkb = (u16*)(ws + 46137344);                 // 8 MB
  u16* Vkb = (u16*)(ws + 54525952);                 // 8 MB
  u16* Kr  = (u16*)(ws + 62914560);                 // 8 MB
  u16* Qr  = (u16*)(ws + 71303168);                 // 8 MB  (total ~76 MB)
  float* Mc = (float*)(ws + 8388608);               // alias WbT (dead after GEMM0)
  u16* Ob = (u16*)(ws + 0);                         // alias Xb  (dead after GEMM0)
  (void)in_sizes; (void)n_in; (void)out_size; (void)ws_size;

  // 1. X -> bf16
  k_f32_to_bf16<<<dim3(4096), dim3(256), 0, stream>>>(X, Xb, 1048576);
  // 2. weights -> transposed bf16 (merged)
  k_transpose3<<<dim3(96, 16), dim3(256), 0, stream>>>(
      w_qkv, w_kvkv, w_out, WbT, WbT + (size_t)3072 * 1024, WoT);
  // 3. fused projection GEMM (128x256 tiles, counted-vmcnt) -> Q, rot(K), V^T, Kk, Vk
  k_gemm0_v3<<<dim3(640), dim3(512), 0, stream>>>(Xb, WbT, Qb, Kr, Vtb, Kkb, Vkb);
  // 4. per-chunk outer-product sums
  k_chunk_outer<<<dim3(512), dim3(256), 0, stream>>>(Kkb, Vkb, Mc);
  // 5. fused prefix + norm + y + rotary -> Qr
  k_chunk_fused<<<dim3(512), dim3(256), 0, stream>>>(Qb, Kkb, Vkb, Mc, Qr);
  // 6. causal flash attention (512 blocks: phase split on z)
  k_attn3<<<dim3(32, 8, 2), dim3(512), 0, stream>>>(Qr, Kr, Vtb, Ob);
  // 7. output projection + bias (64x128 tiles, 512 blocks)
  k_gemm_out<<<dim3(8, 64), dim3(256), 0, stream>>>(Ob, WoT, b_out, out);
}

// Round 12
// 183.253 us; speedup vs baseline: 1.0641x; 1.0641x over previous
//
#include <hip/hip_runtime.h>

typedef unsigned int u32;
typedef unsigned short u16;
typedef __attribute__((ext_vector_type(8))) __bf16 bf16x8;
typedef __attribute__((ext_vector_type(4))) float f32x4;

constexpr int NH = 16;        // heads
constexpr int HDM = 64;       // head dim
constexpr int NSQ = 2048;     // sequence length
constexpr int KD = 1024;      // model dim / GEMM K
constexpr int BHT = 32;       // B*H
constexpr float ROT_C = 13.287712379549449f / 32.0f;  // log2(10000)/32

__device__ __forceinline__ u16 f2bf(float f) {
  u32 u = __float_as_uint(f);
  u += 0x7fffu + ((u >> 16) & 1u);
  return (u16)(u >> 16);
}
__device__ __forceinline__ float bf2f(u16 h) {
  return __uint_as_float(((u32)h) << 16);
}

// fast hw sincos (v_fract + v_sin/v_cos, no libm scratch path).
__device__ __forceinline__ void fast_sincos(float th, float* s, float* c) {
  __sincosf(th, s, c);
}

__device__ __forceinline__ void gl_lds16(const u16* g, u16* l) {
  __builtin_amdgcn_global_load_lds(
      (const __attribute__((address_space(1))) u32*)g,
      (__attribute__((address_space(3))) u32*)l, 16, 0, 0);
}

// swizzled bf16x8 fragment read: row-major tile, row stride rs bytes, 16B chunk cb
__device__ __forceinline__ bf16x8 ldf(const u16* b, int row, int cb, int rs) {
  return *(const bf16x8*)((const char*)b + row * rs + ((cb * 16) ^ ((row & 7) << 4)));
}

// ---------------- elementwise f32 -> bf16 ----------------
__global__ void k_f32_to_bf16(const float* __restrict__ src, u16* __restrict__ dst, int n4) {
  int i = blockIdx.x * 256 + threadIdx.x;
  if (i < n4) {
    float4 v = ((const float4*)src)[i];
    ushort4 o;
    o.x = f2bf(v.x); o.y = f2bf(v.y); o.z = f2bf(v.z); o.w = f2bf(v.w);
    ((ushort4*)dst)[i] = o;
  }
}

// ---------------- merged transpose+convert of the 3 weight tensors ----------------
__global__ void k_transpose3(const float* __restrict__ s0, const float* __restrict__ s1,
                             const float* __restrict__ s2, u16* __restrict__ d0,
                             u16* __restrict__ d1, u16* __restrict__ d2) {
  __shared__ float tile[64][65];
  int bx = blockIdx.x, kt = blockIdx.y * 64;
  const float* src; u16* dst; int srcld, ct;
  if (bx < 48)      { src = s0; dst = d0; srcld = 3072; ct = bx * 64; }
  else if (bx < 80) { src = s1; dst = d1; srcld = 4096; ct = (bx - 48) * 64; }
  else              { src = s2; dst = d2; srcld = 1024; ct = (bx - 80) * 64; }
  int lc = threadIdx.x & 63, rg = threadIdx.x >> 6;
#pragma unroll
  for (int i = 0; i < 16; ++i) {
    int kl = rg * 16 + i;
    tile[kl][lc] = src[(size_t)(kt + kl) * srcld + ct + lc];
  }
  __syncthreads();
#pragma unroll
  for (int i = 0; i < 16; ++i) {
    int cl = rg * 16 + i;
    dst[(size_t)(ct + cl) * 1024 + kt + lc] = f2bf(tile[lc][cl]);
  }
}

// ================= projection GEMM: 128x256 tile, BK=64, coarse counted-vmcnt =================
__device__ __forceinline__ void stage_v3(const u16* __restrict__ gA, const u16* __restrict__ gB,
                                         u16* AL, u16* BL, int mb, int nb, int kt, int tid) {
#pragma unroll
  for (int l = 0; l < 2; ++l) {
    int i = tid + l * 512;          // chunk index 0..1023
    int row = i >> 3, cb = i & 7;
    int col = (cb ^ (row & 7)) << 3;
    gl_lds16(gA + (size_t)(mb + row) * KD + kt * 64 + col, AL + i * 8);
  }
#pragma unroll
  for (int l = 0; l < 4; ++l) {
    int i = tid + l * 512;          // chunk index 0..2047
    int row = i >> 3, cb = i & 7;
    int col = (cb ^ (row & 7)) << 3;
    gl_lds16(gB + (size_t)(nb + row) * KD + kt * 64 + col, BL + i * 8);
  }
}

__device__ __forceinline__ void compute_v3(const u16* AL, const u16* BL,
                                           f32x4 (&acc)[4][4], int wr, int wc, int g, int q) {
#pragma unroll
  for (int ks = 0; ks < 2; ++ks) {
    bf16x8 af[4], bfr[4];
#pragma unroll
    for (int nf = 0; nf < 4; ++nf)
      bfr[nf] = ldf(BL, wc * 64 + nf * 16 + q, ks * 4 + g, 128);
#pragma unroll
    for (int mf = 0; mf < 4; ++mf)
      af[mf] = ldf(AL, wr * 64 + mf * 16 + q, ks * 4 + g, 128);
    __builtin_amdgcn_s_setprio(1);
#pragma unroll
    for (int mf = 0; mf < 4; ++mf)
#pragma unroll
      for (int nf = 0; nf < 4; ++nf)
        acc[mf][nf] = __builtin_amdgcn_mfma_f32_16x16x32_bf16(af[mf], bfr[nf], acc[mf][nf], 0, 0, 0);
    __builtin_amdgcn_s_setprio(0);
  }
}

__global__ __launch_bounds__(512) void k_gemm0_v3(const u16* __restrict__ A,
                                                  const u16* __restrict__ Bt,
                                                  u16* __restrict__ o0, u16* __restrict__ o1,
                                                  u16* __restrict__ o2, u16* __restrict__ o3,
                                                  u16* __restrict__ o4) {
  __shared__ __align__(16) u16 AL[2][8192];    // 128 x 64
  __shared__ __align__(16) u16 BL[2][16384];   // 256 x 64
  int bid = blockIdx.x;
  int swz = (bid & 7) * 80 + (bid >> 3);       // XCD-bijective (640 % 8 == 0)
  int nt = swz % 20, mt = swz / 20;            // nt in [0,20), mt in [0,32)
  int tid = threadIdx.x, w = tid >> 6, lane = tid & 63;
  int g = lane >> 4, q = lane & 15;
  int wr = w >> 2, wc = w & 3;                 // 2 M-waves x 4 N-waves
  int mb = mt * 128, nb = nt * 256;

  f32x4 acc[4][4];
#pragma unroll
  for (int m = 0; m < 4; ++m)
#pragma unroll
    for (int n = 0; n < 4; ++n) acc[m][n] = (f32x4){0.f, 0.f, 0.f, 0.f};

  stage_v3(A, Bt, AL[0], BL[0], mb, nb, 0, tid);
  stage_v3(A, Bt, AL[1], BL[1], mb, nb, 1, tid);
  asm volatile("s_waitcnt vmcnt(6)" ::: "memory");
  asm volatile("s_barrier" ::: "memory");
  __builtin_amdgcn_sched_barrier(0);

#define GBODY(KT, PBUF)                                                     \
  {                                                                         \
    compute_v3(AL[PBUF], BL[PBUF], acc, wr, wc, g, q);                      \
    asm volatile("s_barrier" ::: "memory");                                 \
    if ((KT) + 2 < 16) {                                                    \
      stage_v3(A, Bt, AL[PBUF], BL[PBUF], mb, nb, (KT) + 2, tid);           \
      asm volatile("s_waitcnt vmcnt(6)" ::: "memory");                      \
    } else if ((KT) == 14) {                                                \
      asm volatile("s_waitcnt vmcnt(0)" ::: "memory");                      \
    }                                                                       \
    asm volatile("s_barrier" ::: "memory");                                 \
    __builtin_amdgcn_sched_barrier(0);                                      \
  }

  for (int it = 0; it < 8; ++it) {
    GBODY(2 * it, 0);
    GBODY(2 * it + 1, 1);
  }
#undef GBODY

  // epilogue: 5-way split per column-tensor
#pragma unroll
  for (int nf = 0; nf < 4; ++nf) {
    int c = nt * 256 + wc * 64 + nf * 16 + q;
    int t = c >> 10;
    if (t == 1) {
      // K: fused rotary, write Kr [b][h][n][d]
      int rem = c & 1023;
      int hh = rem >> 6, dd = rem & 63;
      float invf = exp2f(-(float)(dd >> 1) * ROT_C);
      float sgn = (dd & 1) ? 1.0f : -1.0f;
      size_t hoff = (size_t)hh * NSQ * HDM + dd;
#pragma unroll
      for (int mf = 0; mf < 4; ++mf)
#pragma unroll
        for (int r = 0; r < 4; ++r) {
          int row = mt * 128 + wr * 64 + mf * 16 + g * 4 + r;
          int b = row >> 11, nn = row & 2047;
          float mine = acc[mf][nf][r];
          float part = __shfl_xor(mine, 1);
          float s, cc;
          fast_sincos((float)nn * invf, &s, &cc);
          o1[(size_t)b * NH * NSQ * HDM + hoff + (size_t)nn * HDM] = f2bf(mine * cc + sgn * part * s);
        }
    } else if (t == 2) {
      // V -> transposed [bh][d][n]
      int rem = c & 1023;
      int hh = rem >> 6, dd = rem & 63;
#pragma unroll
      for (int mf = 0; mf < 4; ++mf)
#pragma unroll
        for (int r = 0; r < 4; ++r) {
          int row = mt * 128 + wr * 64 + mf * 16 + g * 4 + r;
          int b = row >> 11, nn = row & 2047;
          o2[((size_t)(b * NH + hh) * HDM + dd) * NSQ + nn] = f2bf(acc[mf][nf][r]);
        }
    } else {
      u16* dst = (t == 0) ? o0 : ((t == 3) ? o3 : o4);
      int rem = c & 1023;
      size_t hoff = (size_t)(rem >> 6) * NSQ * HDM + (rem & 63);
#pragma unroll
      for (int mf = 0; mf < 4; ++mf)
#pragma unroll
        for (int r = 0; r < 4; ++r) {
          int row = mt * 128 + wr * 64 + mf * 16 + g * 4 + r;
          int b = row >> 11, nn = row & 2047;
          dst[(size_t)b * NH * NSQ * HDM + hoff + (size_t)nn * HDM] = f2bf(acc[mf][nf][r]);
        }
    }
  }
}

// ================= output GEMM: 64x128 tile, m97 schedule, 512 blocks =================
__device__ __forceinline__ void gemm_stage_o(const u16* __restrict__ A, const u16* __restrict__ Bt,
                                             u16* Albuf, u16* Blbuf, int mt, int nt, int kt,
                                             int tid) {
  {
    int i = tid;                       // A: 64x32 = 256 chunks
    int row = i >> 2;
    int ke = (i & 3) * 8;
    int grow = mt * 64 + row;
    int k = kt * 32 + ke;
    const u16* ga = A + ((size_t)((grow >> 11) * NH + (k >> 6)) * NSQ + (grow & 2047)) * HDM + (k & 63);
    gl_lds16(ga, Albuf + i * 8);
  }
#pragma unroll
  for (int l = 0; l < 2; ++l) {        // B: 128x32 = 512 chunks
    int i = tid + l * 256;
    int row = i >> 2;
    int ke = (i & 3) * 8;
    const u16* gb = Bt + (size_t)(nt * 128 + row) * KD + kt * 32 + ke;
    gl_lds16(gb, Blbuf + i * 8);
  }
}

__device__ __forceinline__ void gemm_compute_o(const u16* Albuf, const u16* Blbuf,
                                               f32x4 acc[2][4], int wr, int wc, int g, int q) {
  bf16x8 af[2], bfr[4];
#pragma unroll
  for (int m = 0; m < 2; ++m)
    af[m] = *(const bf16x8*)(Albuf + (wr * 32 + m * 16 + q) * 32 + g * 8);
#pragma unroll
  for (int n = 0; n < 4; ++n)
    bfr[n] = *(const bf16x8*)(Blbuf + (wc * 64 + n * 16 + q) * 32 + g * 8);
#pragma unroll
  for (int m = 0; m < 2; ++m)
#pragma unroll
    for (int n = 0; n < 4; ++n)
      acc[m][n] = __builtin_amdgcn_mfma_f32_16x16x32_bf16(af[m], bfr[n], acc[m][n], 0, 0, 0);
}

__global__ __launch_bounds__(256) void k_gemm_out(const u16* __restrict__ A, const u16* __restrict__ Bt,
                                                  const float* __restrict__ bias,
                                                  float* __restrict__ Cout) {
  __shared__ __align__(16) u16 Al[2][2048];    // 64 x 32
  __shared__ __align__(16) u16 Bl[2][4096];    // 128 x 32
  int nt = blockIdx.x, mt = blockIdx.y;
  int tid = threadIdx.x, w = tid >> 6, lane = tid & 63;
  int g = lane >> 4, q = lane & 15, wr = w >> 1, wc = w & 1;
  f32x4 acc[2][4];
#pragma unroll
  for (int m = 0; m < 2; ++m)
#pragma unroll
    for (int n = 0; n < 4; ++n) acc[m][n] = (f32x4){0.f, 0.f, 0.f, 0.f};

  gemm_stage_o(A, Bt, Al[0], Bl[0], mt, nt, 0, tid);
  __syncthreads();
  int cur = 0;
  for (int kt = 1; kt < 32; ++kt) {
    gemm_stage_o(A, Bt, Al[cur ^ 1], Bl[cur ^ 1], mt, nt, kt, tid);
    gemm_compute_o(Al[cur], Bl[cur], acc, wr, wc, g, q);
    __syncthreads();
    cur ^= 1;
  }
  gemm_compute_o(Al[cur], Bl[cur], acc, wr, wc, g, q);

#pragma unroll
  for (int nf = 0; nf < 4; ++nf) {
    int c = nt * 128 + wc * 64 + nf * 16 + q;
    float bv = bias[c];
#pragma unroll
    for (int mf = 0; mf < 2; ++mf)
#pragma unroll
      for (int r = 0; r < 4; ++r) {
        int row = mt * 64 + wr * 32 + mf * 16 + g * 4 + r;
        Cout[(size_t)row * 1024 + c] = acc[mf][nf][r] + bv;
      }
  }
}

// ---------------- chunk pass 1: per-chunk sum of outer products kk ⊗ vk ----------------
__global__ __launch_bounds__(256) void k_chunk_outer(const u16* __restrict__ Kk,
                                                     const u16* __restrict__ Vk,
                                                     float* __restrict__ Mc) {
  int bhc = blockIdx.x;  // 512 = bh*16 + c
  __shared__ float kk[128][64];
  __shared__ float vv[128][64];
  int tid = threadIdx.x;
  size_t base = ((size_t)(bhc >> 4) * NSQ + (size_t)(bhc & 15) * 128) * HDM;
  for (int i = tid; i < 2048; i += 256) {
    int r = i >> 4, c4 = (i & 15) * 4;
    ushort4 a = ((const ushort4*)(Kk + base))[i];
    kk[r][c4] = bf2f(a.x); kk[r][c4 + 1] = bf2f(a.y); kk[r][c4 + 2] = bf2f(a.z); kk[r][c4 + 3] = bf2f(a.w);
    ushort4 b = ((const ushort4*)(Vk + base))[i];
    vv[r][c4] = bf2f(b.x); vv[r][c4 + 1] = bf2f(b.y); vv[r][c4 + 2] = bf2f(b.z); vv[r][c4 + 3] = bf2f(b.w);
  }
  __syncthreads();
  int i0 = (tid >> 4) * 4, j0 = (tid & 15) * 4;
  float a2[4][4];
#pragma unroll
  for (int di = 0; di < 4; ++di)
#pragma unroll
    for (int dj = 0; dj < 4; ++dj) a2[di][dj] = 0.f;
  for (int m = 0; m < 128; ++m) {
    float ka[4], vb[4];
#pragma unroll
    for (int d = 0; d < 4; ++d) { ka[d] = kk[m][i0 + d]; vb[d] = vv[m][j0 + d]; }
#pragma unroll
    for (int di = 0; di < 4; ++di)
#pragma unroll
      for (int dj = 0; dj < 4; ++dj) a2[di][dj] += ka[di] * vb[dj];
  }
  float* out = Mc + (size_t)bhc * 4096;
#pragma unroll
  for (int di = 0; di < 4; ++di) {
    float4 v = make_float4(a2[di][0], a2[di][1], a2[di][2], a2[di][3]);
    *(float4*)(out + (i0 + di) * 64 + j0) = v;
  }
}

// ---------------- chunk pass 2: exclusive prefix of chunk states (parallel rows) ----------------
__global__ __launch_bounds__(256) void k_chunk_prefix2(const float* __restrict__ Mc,
                                                       float* __restrict__ Sst) {
  int bh = blockIdx.x, rg = blockIdx.y;
  int tid = threadIdx.x;
  int r8 = tid >> 5, cp = tid & 31;
  int i = rg * 8 + r8, j0 = cp * 2;
  float s0 = (i == j0) ? 8.0f : 0.0f;
  float s1 = (i == j0 + 1) ? 8.0f : 0.0f;
  size_t rowoff = (size_t)i * 64 + j0;
  for (int c = 0; c < 16; ++c) {
    size_t o = ((size_t)bh * 16 + c) * 4096 + rowoff;
    *(float2*)(Sst + o) = make_float2(s0, s1);
    float2 mv = *(const float2*)(Mc + o);
    s0 += mv.x; s1 += mv.y;
  }
}

// ---------------- chunk norms via MFMA: invn[n] = 1/(||S_n||_F + 1e-8) ----------------
__global__ __launch_bounds__(256) void k_chunk_norm(const u16* __restrict__ Kk,
                                                    const u16* __restrict__ Vk,
                                                    const float* __restrict__ Sst,
                                                    float* __restrict__ Invn) {
  __shared__ __align__(16) u16 KkL[128 * 64];
  __shared__ __align__(16) u16 VkL[128 * 64];
  __shared__ __align__(16) u16 SL[64 * 64];
  __shared__ float prebuf[128][2];
  __shared__ float bilbuf[128][2];
  __shared__ float sc[128];
  __shared__ float red[4];
  int bhc = blockIdx.x;
  int tid = threadIdx.x, w = tid >> 6, lane = tid & 63;
  int g = lane >> 4, q = lane & 15;
  size_t base = (size_t)bhc * 8192;

  for (int ic = tid; ic < 1024; ic += 256) {
    int row = ic >> 3, cb = ic & 7;
    int off = row * 128 + ((cb * 16) ^ ((row & 7) << 4));
    *(uint4*)((char*)KkL + off) = ((const uint4*)(Kk + base))[ic];
    *(uint4*)((char*)VkL + off) = ((const uint4*)(Vk + base))[ic];
  }
  float ss = 0.f;
  const float4* Sg = (const float4*)(Sst + (size_t)bhc * 4096);
  for (int i = tid; i < 1024; i += 256) {
    float4 v = Sg[i];
    ss += v.x * v.x + v.y * v.y + v.z * v.z + v.w * v.w;
    int row = i >> 4, c8 = (i & 15) * 8;  // byte col
    u32 lo = (u32)f2bf(v.x) | ((u32)f2bf(v.y) << 16);
    u32 hi = (u32)f2bf(v.z) | ((u32)f2bf(v.w) << 16);
    *(uint2*)((char*)SL + row * 128 + (c8 ^ ((row & 7) << 4))) = make_uint2(lo, hi);
  }
#pragma unroll
  for (int d = 1; d < 64; d <<= 1) ss += __shfl_xor(ss, d);
  if (lane == 0) red[w] = ss;
  __syncthreads();

  int wr = w >> 1, wc = w & 1;
  bf16x8 ka[4][2], va[4][2];
#pragma unroll
  for (int mf = 0; mf < 4; ++mf)
#pragma unroll
    for (int ks = 0; ks < 2; ++ks) {
      ka[mf][ks] = ldf(KkL, wr * 64 + mf * 16 + q, ks * 4 + g, 128);
      va[mf][ks] = ldf(VkL, wr * 64 + mf * 16 + q, ks * 4 + g, 128);
    }

  float pracc[4][4];
#pragma unroll
  for (int mf = 0; mf < 4; ++mf)
#pragma unroll
    for (int r = 0; r < 4; ++r) pracc[mf][r] = 0.f;
  for (int pf = 0; pf < 4; ++pf) {
    bf16x8 kb0 = ldf(KkL, wc * 64 + pf * 16 + q, g, 128);
    bf16x8 kb1 = ldf(KkL, wc * 64 + pf * 16 + q, 4 + g, 128);
    bf16x8 vb0 = ldf(VkL, wc * 64 + pf * 16 + q, g, 128);
    bf16x8 vb1 = ldf(VkL, wc * 64 + pf * 16 + q, 4 + g, 128);
#pragma unroll
    for (int mf = 0; mf < 4; ++mf) {
      f32x4 a1 = (f32x4){0.f, 0.f, 0.f, 0.f}, b1 = (f32x4){0.f, 0.f, 0.f, 0.f};
      a1 = __builtin_amdgcn_mfma_f32_16x16x32_bf16(ka[mf][0], kb0, a1, 0, 0, 0);
      a1 = __builtin_amdgcn_mfma_f32_16x16x32_bf16(ka[mf][1], kb1, a1, 0, 0, 0);
      b1 = __builtin_amdgcn_mfma_f32_16x16x32_bf16(va[mf][0], vb0, b1, 0, 0, 0);
      b1 = __builtin_amdgcn_mfma_f32_16x16x32_bf16(va[mf][1], vb1, b1, 0, 0, 0);
#pragma unroll
      for (int r = 0; r < 4; ++r) {
        int m = wr * 64 + mf * 16 + g * 4 + r;
        int p = wc * 64 + pf * 16 + q;
        float gv = a1[r] * b1[r];
        float coef = (p < m) ? 1.f : ((p == m) ? 0.5f : 0.f);
        pracc[mf][r] += coef * gv;
      }
    }
  }
#pragma unroll
  for (int mf = 0; mf < 4; ++mf)
#pragma unroll
    for (int r = 0; r < 4; ++r) {
      float v = pracc[mf][r];
      v += __shfl_xor(v, 1); v += __shfl_xor(v, 2); v += __shfl_xor(v, 4); v += __shfl_xor(v, 8);
      pracc[mf][r] = v;
    }
  if (q == 0) {
#pragma unroll
    for (int mf = 0; mf < 4; ++mf)
#pragma unroll
      for (int r = 0; r < 4; ++r) prebuf[wr * 64 + mf * 16 + g * 4 + r][wc] = pracc[mf][r];
  }

  float bacc[4][4];
#pragma unroll
  for (int mf = 0; mf < 4; ++mf)
#pragma unroll
    for (int r = 0; r < 4; ++r) bacc[mf][r] = 0.f;
  for (int jf = 0; jf < 2; ++jf) {
    bf16x8 sb0 = ldf(SL, wc * 32 + jf * 16 + q, g, 128);
    bf16x8 sb1 = ldf(SL, wc * 32 + jf * 16 + q, 4 + g, 128);
#pragma unroll
    for (int mf = 0; mf < 4; ++mf) {
      f32x4 u = (f32x4){0.f, 0.f, 0.f, 0.f};
      u = __builtin_amdgcn_mfma_f32_16x16x32_bf16(va[mf][0], sb0, u, 0, 0, 0);
      u = __builtin_amdgcn_mfma_f32_16x16x32_bf16(va[mf][1], sb1, u, 0, 0, 0);
#pragma unroll
      for (int r = 0; r < 4; ++r) {
        int m = wr * 64 + mf * 16 + g * 4 + r;
        int j = wc * 32 + jf * 16 + q;
        float kkv = bf2f(*(const u16*)((const char*)KkL + m * 128 + ((j * 2) ^ ((m & 7) << 4))));
        bacc[mf][r] += u[r] * kkv;
      }
    }
  }
#pragma unroll
  for (int mf = 0; mf < 4; ++mf)
#pragma unroll
    for (int r = 0; r < 4; ++r) {
      float v = bacc[mf][r];
      v += __shfl_xor(v, 1); v += __shfl_xor(v, 2); v += __shfl_xor(v, 4); v += __shfl_xor(v, 8);
      bacc[mf][r] = v;
    }
  if (q == 0) {
#pragma unroll
    for (int mf = 0; mf < 4; ++mf)
#pragma unroll
      for (int r = 0; r < 4; ++r) bilbuf[wr * 64 + mf * 16 + g * 4 + r][wc] = bacc[mf][r];
  }
  __syncthreads();

  if (tid < 128)
    sc[tid] = 2.f * (prebuf[tid][0] + prebuf[tid][1] + bilbuf[tid][0] + bilbuf[tid][1]);
  __syncthreads();
  for (int off = 1; off < 128; off <<= 1) {
    float add = 0.f;
    if (tid < 128 && tid >= off) add = sc[tid - off];
    __syncthreads();
    if (tid < 128) sc[tid] += add;
    __syncthreads();
  }
  if (tid < 128) {
    float n0 = red[0] + red[1] + red[2] + red[3];
    float cum = n0 + sc[tid];
    Invn[(size_t)bhc * 128 + tid] = 1.f / (sqrtf(cum) + 1e-8f);
  }
}

// ---------------- chunk y via MFMA + fused rotary/scale: Qr = rot(Y*invn)*0.125 ----------------
__global__ __launch_bounds__(256) void k_chunk_yv2(const u16* __restrict__ Qb,
                                                   const u16* __restrict__ Kk,
                                                   const u16* __restrict__ Vk,
                                                   const float* __restrict__ Sst,
                                                   const float* __restrict__ Invn,
                                                   u16* __restrict__ Qro) {
  __shared__ __align__(16) u16 QL[128 * 64];
  __shared__ __align__(16) u16 WL[128 * 64];  // Vk, then KkT
  __shared__ __align__(16) u16 SL[64 * 64];
  __shared__ __align__(16) u16 PL[128 * 128];
  __shared__ float inv[128];
  int bhc = blockIdx.x;
  int tid = threadIdx.x, w = tid >> 6, lane = tid & 63;
  int g = lane >> 4, q = lane & 15;
  size_t base = (size_t)bhc * 8192;

  for (int ic = tid; ic < 1024; ic += 256) {
    int row = ic >> 3, cb = ic & 7;
    int off = row * 128 + ((cb * 16) ^ ((row & 7) << 4));
    *(uint4*)((char*)QL + off) = ((const uint4*)(Qb + base))[ic];
    *(uint4*)((char*)WL + off) = ((const uint4*)(Vk + base))[ic];
  }
  const float4* Sg = (const float4*)(Sst + (size_t)bhc * 4096);
  for (int i = tid; i < 1024; i += 256) {
    float4 v = Sg[i];
    int row = i >> 4, c8 = (i & 15) * 8;
    u32 lo = (u32)f2bf(v.x) | ((u32)f2bf(v.y) << 16);
    u32 hi = (u32)f2bf(v.z) | ((u32)f2bf(v.w) << 16);
    *(uint2*)((char*)SL + row * 128 + (c8 ^ ((row & 7) << 4))) = make_uint2(lo, hi);
  }
  if (tid < 128) inv[tid] = Invn[(size_t)bhc * 128 + tid];
  __syncthreads();

  int wr = w >> 1, wc = w & 1;
  f32x4 pacc[4][4];
#pragma unroll
  for (int mf = 0; mf < 4; ++mf)
#pragma unroll
    for (int nf = 0; nf < 4; ++nf) pacc[mf][nf] = (f32x4){0.f, 0.f, 0.f, 0.f};
#pragma unroll
  for (int ks = 0; ks < 2; ++ks) {
    bf16x8 av[4], bq[4];
#pragma unroll
    for (int mf = 0; mf < 4; ++mf) av[mf] = ldf(WL, wr * 64 + mf * 16 + q, ks * 4 + g, 128);
#pragma unroll
    for (int nf = 0; nf < 4; ++nf) bq[nf] = ldf(QL, wc * 64 + nf * 16 + q, ks * 4 + g, 128);
#pragma unroll
    for (int mf = 0; mf < 4; ++mf)
#pragma unroll
      for (int nf = 0; nf < 4; ++nf)
        pacc[mf][nf] = __builtin_amdgcn_mfma_f32_16x16x32_bf16(av[mf], bq[nf], pacc[mf][nf], 0, 0, 0);
  }
#pragma unroll
  for (int mf = 0; mf < 4; ++mf)
#pragma unroll
    for (int nf = 0; nf < 4; ++nf) {
      int m0 = wr * 64 + mf * 16 + g * 4;
      int n = wc * 64 + nf * 16 + q;
      float v0 = (m0 + 0 <= n) ? pacc[mf][nf][0] : 0.f;
      float v1 = (m0 + 1 <= n) ? pacc[mf][nf][1] : 0.f;
      float v2 = (m0 + 2 <= n) ? pacc[mf][nf][2] : 0.f;
      float v3 = (m0 + 3 <= n) ? pacc[mf][nf][3] : 0.f;
      u32 lo = (u32)f2bf(v0) | ((u32)f2bf(v1) << 16);
      u32 hi = (u32)f2bf(v2) | ((u32)f2bf(v3) << 16);
      *(uint2*)((char*)PL + n * 256 + ((m0 * 2) ^ ((n & 7) << 4))) = make_uint2(lo, hi);
    }
  __syncthreads();
  for (int i = tid; i < 2048; i += 256) {
    int r = i >> 4, c4 = (i & 15) * 4;
    ushort4 kv = ((const ushort4*)(Kk + base))[i];
    *(u16*)((char*)WL + (c4 + 0) * 256 + ((r * 2) ^ (((c4 + 0) & 7) << 4))) = kv.x;
    *(u16*)((char*)WL + (c4 + 1) * 256 + ((r * 2) ^ (((c4 + 1) & 7) << 4))) = kv.y;
    *(u16*)((char*)WL + (c4 + 2) * 256 + ((r * 2) ^ (((c4 + 2) & 7) << 4))) = kv.z;
    *(u16*)((char*)WL + (c4 + 3) * 256 + ((r * 2) ^ (((c4 + 3) & 7) << 4))) = kv.w;
  }
  __syncthreads();

  f32x4 yacc[4][2];
#pragma unroll
  for (int nf = 0; nf < 4; ++nf)
#pragma unroll
    for (int jf = 0; jf < 2; ++jf) yacc[nf][jf] = (f32x4){0.f, 0.f, 0.f, 0.f};
#pragma unroll
  for (int ks = 0; ks < 2; ++ks) {
    bf16x8 aq[4], bs[2];
#pragma unroll
    for (int nf = 0; nf < 4; ++nf) aq[nf] = ldf(QL, wr * 64 + nf * 16 + q, ks * 4 + g, 128);
#pragma unroll
    for (int jf = 0; jf < 2; ++jf) bs[jf] = ldf(SL, wc * 32 + jf * 16 + q, ks * 4 + g, 128);
#pragma unroll
    for (int nf = 0; nf < 4; ++nf)
#pragma unroll
      for (int jf = 0; jf < 2; ++jf)
        yacc[nf][jf] = __builtin_amdgcn_mfma_f32_16x16x32_bf16(aq[nf], bs[jf], yacc[nf][jf], 0, 0, 0);
  }
#pragma unroll
  for (int ks = 0; ks < 4; ++ks) {
    bf16x8 ap[4], bk[2];
#pragma unroll
    for (int nf = 0; nf < 4; ++nf) ap[nf] = ldf(PL, wr * 64 + nf * 16 + q, ks * 4 + g, 256);
#pragma unroll
    for (int jf = 0; jf < 2; ++jf) bk[jf] = ldf(WL, wc * 32 + jf * 16 + q, ks * 4 + g, 256);
#pragma unroll
    for (int nf = 0; nf < 4; ++nf)
#pragma unroll
      for (int jf = 0; jf < 2; ++jf)
        yacc[nf][jf] = __builtin_amdgcn_mfma_f32_16x16x32_bf16(ap[nf], bk[jf], yacc[nf][jf], 0, 0, 0);
  }
  // epilogue: *inv[n], rotary (pair via shfl_xor 1), *0.125, write Qro
#pragma unroll
  for (int nf = 0; nf < 4; ++nf)
#pragma unroll
    for (int jf = 0; jf < 2; ++jf) {
      int j = wc * 32 + jf * 16 + q;
      float invf = exp2f(-(float)(j >> 1) * ROT_C);
      float sgn = (j & 1) ? 1.0f : -1.0f;
#pragma unroll
      for (int r = 0; r < 4; ++r) {
        int n = wr * 64 + nf * 16 + g * 4 + r;
        float val = yacc[nf][jf][r] * inv[n];
        float part = __shfl_xor(val, 1);
        int ng = (bhc & 15) * 128 + n;
        float s, cc;
        fast_sincos((float)ng * invf, &s, &cc);
        Qro[base + (size_t)n * 64 + j] = f2bf((val * cc + sgn * part * s) * 0.125f);
      }
    }
}

// ---------------- causal flash attention v3: phase split across blockIdx.z ----------------
__global__ __launch_bounds__(512) void k_attn3(const u16* __restrict__ Qr, const u16* __restrict__ Kr,
                                               const u16* __restrict__ Vt, u16* __restrict__ Ob) {
  __shared__ __align__(16) u16 QL[128 * 64];
  __shared__ __align__(16) u16 KL[2][64 * 64];
  __shared__ __align__(16) u16 VL[2][64 * 64];
  __shared__ __align__(16) u16 PLa[8][16 * 64];
  int bh = blockIdx.x, pair = blockIdx.y, phase = blockIdx.z;
  int tid = threadIdx.x, w = tid >> 6, lane = tid & 63;
  int g = lane >> 4, q16 = lane & 15;
  const u16* Qg_base = Qr + (size_t)bh * NSQ * HDM;
  const u16* Kg_base = Kr + (size_t)bh * NSQ * HDM;
  const u16* VTg_base = Vt + (size_t)bh * HDM * NSQ;  // [d][n]
  u16* Og_base = Ob + (size_t)bh * NSQ * HDM;
  u16* Pw = PLa[w];
  int srow = tid >> 3, scb = tid & 7;  // staging row/chunk for 64x64 tiles

  int t = phase ? (15 - pair) : pair;
  int qbase = t * 128;
  int nkt = 2 * t + 2;
  int lastkt_w = (qbase + w * 16 + 15) >> 6;
  int qg_ = qbase + w * 16 + q16;

  {
    const u16* Qg = Qg_base + qbase * 64;
#pragma unroll
    for (int it = 0; it < 2; ++it) {
      int c = it * 512 + tid;
      int row = c >> 3, cb = c & 7;
      gl_lds16(Qg + row * 64 + ((cb ^ (row & 7)) << 3), QL + c * 8);
    }
  }
  gl_lds16(Kg_base + srow * 64 + ((scb ^ (srow & 7)) << 3), KL[0] + tid * 8);
  gl_lds16(VTg_base + (size_t)srow * NSQ + ((scb ^ (srow & 7)) << 3), VL[0] + tid * 8);
  __syncthreads();

  bf16x8 qf[2];
  qf[0] = ldf(QL, w * 16 + q16, g, 128);
  qf[1] = ldf(QL, w * 16 + q16, 4 + g, 128);

  f32x4 o[4];
#pragma unroll
  for (int df = 0; df < 4; ++df) o[df] = (f32x4){0.f, 0.f, 0.f, 0.f};
  float m_run = -3.0e38f, l_run = 0.f;

  int cur = 0;
  for (int kt = 0; kt < nkt; ++kt) {
    if (kt + 1 < nkt) {
      gl_lds16(Kg_base + (kt + 1) * 4096 + srow * 64 + ((scb ^ (srow & 7)) << 3),
               KL[cur ^ 1] + tid * 8);
      gl_lds16(VTg_base + (size_t)srow * NSQ + (kt + 1) * 64 + ((scb ^ (srow & 7)) << 3),
               VL[cur ^ 1] + tid * 8);
    }
    if (kt <= lastkt_w) {
      const u16* Kbuf = KL[cur];
      const u16* Vbuf = VL[cur];
      f32x4 st[4];
#pragma unroll
      for (int kf = 0; kf < 4; ++kf) {
        f32x4 s = (f32x4){0.f, 0.f, 0.f, 0.f};
        s = __builtin_amdgcn_mfma_f32_16x16x32_bf16(ldf(Kbuf, kf * 16 + q16, g, 128), qf[0], s, 0, 0, 0);
        s = __builtin_amdgcn_mfma_f32_16x16x32_bf16(ldf(Kbuf, kf * 16 + q16, 4 + g, 128), qf[1], s, 0, 0, 0);
        st[kf] = s;
      }
      float smax = -1e30f;
      bool needmask = (kt * 64 + 63 > qbase + w * 16);
      if (needmask) {
#pragma unroll
        for (int kf = 0; kf < 4; ++kf)
#pragma unroll
          for (int r = 0; r < 4; ++r) {
            int keyg = kt * 64 + kf * 16 + g * 4 + r;
            float sv = st[kf][r];
            sv = (keyg <= qg_) ? sv : -1e30f;
            st[kf][r] = sv;
            smax = fmaxf(smax, sv);
          }
      } else {
#pragma unroll
        for (int kf = 0; kf < 4; ++kf)
#pragma unroll
          for (int r = 0; r < 4; ++r) smax = fmaxf(smax, st[kf][r]);
      }
      smax = fmaxf(smax, __shfl_xor(smax, 16));
      smax = fmaxf(smax, __shfl_xor(smax, 32));
      float mnew = fmaxf(m_run, smax);
      float corr = __expf(m_run - mnew);
      float ls = 0.f;
#pragma unroll
      for (int kf = 0; kf < 4; ++kf)
#pragma unroll
        for (int r = 0; r < 4; ++r) {
          float p = __expf(st[kf][r] - mnew);
          st[kf][r] = p;
          ls += p;
        }
      ls += __shfl_xor(ls, 16);
      ls += __shfl_xor(ls, 32);
      m_run = mnew;
      l_run = l_run * corr + ls;
#pragma unroll
      for (int df = 0; df < 4; ++df) {
        o[df][0] *= corr; o[df][1] *= corr; o[df][2] *= corr; o[df][3] *= corr;
      }
#pragma unroll
      for (int kf = 0; kf < 4; ++kf) {
        u32 lo = (u32)f2bf(st[kf][0]) | ((u32)f2bf(st[kf][1]) << 16);
        u32 hi = (u32)f2bf(st[kf][2]) | ((u32)f2bf(st[kf][3]) << 16);
        int ba = q16 * 128 + ((kf * 32 + g * 8) ^ ((q16 & 7) << 4));
        *(u32*)((char*)Pw + ba) = lo;
        *(u32*)((char*)Pw + ba + 4) = hi;
      }
#pragma unroll
      for (int kc = 0; kc < 2; ++kc) {
        bf16x8 pf = ldf(Pw, q16, kc * 4 + g, 128);
#pragma unroll
        for (int df = 0; df < 4; ++df) {
          bf16x8 vf = ldf(Vbuf, df * 16 + q16, kc * 4 + g, 128);
          o[df] = __builtin_amdgcn_mfma_f32_16x16x32_bf16(vf, pf, o[df], 0, 0, 0);
        }
      }
    }
    __syncthreads();
    cur ^= 1;
  }
  float invl = 1.0f / l_run;
  u16* Og = Og_base + (size_t)(qbase + w * 16 + q16) * HDM;
#pragma unroll
  for (int df = 0; df < 4; ++df)
#pragma unroll
    for (int r = 0; r < 4; ++r) Og[df * 16 + g * 4 + r] = f2bf(o[df][r] * invl);
}

// ---------------- launcher ----------------
extern "C" void kernel_launch(void* const* d_in, const int* in_sizes, int n_in,
                              void* d_out, int out_size, void* d_ws, size_t ws_size,
                              hipStream_t stream) {
  const float* X = (const float*)d_in[0];
  const float* w_qkv = (const float*)d_in[1];
  const float* w_kvkv = (const float*)d_in[2];
  const float* w_out = (const float*)d_in[3];
  const float* b_out = (const float*)d_in[4];
  float* out = (float*)d_out;
  char* ws = (char*)d_ws;

  u16* Xb  = (u16*)(ws + 0);                        // 8 MB   (later aliased by Ob)
  u16* WbT = (u16*)(ws + 8388608);                  // 10 MB  (later aliased by Mc/Invn)
  u16* WoT = (u16*)(ws + 18874368);                 // 2 MB
  u16* Qb  = (u16*)(ws + 20971520);                 // 8 MB
  float* Sst = (float*)(ws + 29360128);             // 8 MB
  u16* Vtb = (u16*)(ws + 37748736);                 // 8 MB (V transposed [bh][d][n])
  u16* Kkb = (u16*)(ws + 46137344);                 // 8 MB
  u16* Vkb = (u16*)(ws + 54525952);                 // 8 MB
  u16* Kr  = (u16*)(ws + 62914560);                 // 8 MB
  u16* Qr  = (u16*)(ws + 71303168);                 // 8 MB  (total ~76 MB)
  float* Mc   = (float*)(ws + 8388608);             // alias WbT (dead after GEMM0)
  float* Invn = (float*)(ws + 16777216);            // alias WbT tail (dead after GEMM0)
  u16* Ob = (u16*)(ws + 0);                         // alias Xb  (dead after GEMM0)
  (void)in_sizes; (void)n_in; (void)out_size; (void)ws_size;

  // 1. X -> bf16
  k_f32_to_bf16<<<dim3(4096), dim3(256), 0, stream>>>(X, Xb, 1048576);
  // 2. weights -> transposed bf16 (merged)
  k_transpose3<<<dim3(96, 16), dim3(256), 0, stream>>>(
      w_qkv, w_kvkv, w_out, WbT, WbT + (size_t)3072 * 1024, WoT);
  // 3. fused projection GEMM (128x256 tiles, counted-vmcnt) -> Q, rot(K), V^T, Kk, Vk
  k_gemm0_v3<<<dim3(640), dim3(512), 0, stream>>>(Xb, WbT, Qb, Kr, Vtb, Kkb, Vkb);
  // 4-6. chunked linear-attention normalizer (parallel prefix + MFMA norm/y)
  k_chunk_outer<<<dim3(512), dim3(256), 0, stream>>>(Kkb, Vkb, Mc);
  k_chunk_prefix2<<<dim3(32, 8), dim3(256), 0, stream>>>(Mc, Sst);
  k_chunk_norm<<<dim3(512), dim3(256), 0, stream>>>(Kkb, Vkb, Sst, Invn);
  k_chunk_yv2<<<dim3(512), dim3(256), 0, stream>>>(Qb, Kkb, Vkb, Sst, Invn, Qr);
  // 7. causal flash attention (512 blocks: phase split on z)
  k_attn3<<<dim3(32, 8, 2), dim3(512), 0, stream>>>(Qr, Kr, Vtb, Ob);
  // 8. output projection + bias (64x128 tiles, 512 blocks)
  k_gemm_out<<<dim3(8, 64), dim3(256), 0, stream>>>(Ob, WoT, b_out, out);
}